// Round 1
// baseline (264.624 us; speedup 1.0000x reference)
//
#include <hip/hip_runtime.h>
#include <hip/hip_bf16.h>

#define SEQ_LEN 2048
#define NBATCH 2
#define DM 1024
#define NH 16
#define HD 64
#define NR (NBATCH * SEQ_LEN)  // 4096 rows
#define NQKV (3 * DM)          // 3072 fused QKV cols
#define LDQK 2048              // QK buffer leading dim (Q cols 0..1023, K 1024..2047)

typedef __attribute__((ext_vector_type(8))) short bf16x8;
typedef __attribute__((ext_vector_type(4))) float f32x4;

__device__ __forceinline__ short f2b(float f) {
    __hip_bfloat16 h = __float2bfloat16(f);
    return *reinterpret_cast<short*>(&h);
}
__device__ __forceinline__ float b2f(short s) {
    union { unsigned u; float f; } x;
    x.u = ((unsigned)(unsigned short)s) << 16;
    return x.f;
}

// async global->LDS 16B copy
__device__ __forceinline__ void gload_lds16(const void* g, void* l) {
    __builtin_amdgcn_global_load_lds(
        (const __attribute__((address_space(1))) unsigned int*)g,
        (__attribute__((address_space(3))) unsigned int*)l, 16, 0, 0);
}

// ---------------------------------------------------------------------------
// Fused fp32->bf16 conversion for all 5 inputs in one launch.
// ---------------------------------------------------------------------------
__global__ __launch_bounds__(256) void cvt_all(
    const float* __restrict__ x,  const float* __restrict__ wq,
    const float* __restrict__ wk, const float* __restrict__ wv,
    const float* __restrict__ wo,
    __hip_bfloat16* __restrict__ xb, __hip_bfloat16* __restrict__ wqkvb,
    __hip_bfloat16* __restrict__ wob) {
    int id = blockIdx.x;
    const float* src; __hip_bfloat16* dst;
    if (id < 4096) { src = x + (size_t)id * 1024; dst = xb + (size_t)id * 1024; }
    else {
        int k = id - 4096, seg = k >> 10;
        size_t off = (size_t)(k & 1023) * 1024;
        if      (seg == 0) { src = wq + off; dst = wqkvb + off; }
        else if (seg == 1) { src = wk + off; dst = wqkvb + (1u << 20) + off; }
        else if (seg == 2) { src = wv + off; dst = wqkvb + (2u << 20) + off; }
        else               { src = wo + off; dst = wob + off; }
    }
    int i = threadIdx.x * 4;
    float4 v = *(const float4*)(src + i);
    dst[i + 0] = __float2bfloat16(v.x);
    dst[i + 1] = __float2bfloat16(v.y);
    dst[i + 2] = __float2bfloat16(v.z);
    dst[i + 3] = __float2bfloat16(v.w);
}

__device__ __forceinline__ void store_c(float* p, float v) { *p = v; }
__device__ __forceinline__ void store_c(__hip_bfloat16* p, float v) {
    *p = __float2bfloat16(v);
}

// ---------------------------------------------------------------------------
// m97-style GEMM: C[M,N] = A[M,K] @ B[N,K]^T, 128x128 tile, BK=32, 4 waves,
// global_load_lds width-16 staging. FUSED=true (QKV projection):
//   blockIdx.y < 16 -> bf16 store into QKb (ldc = 2048)
//   blockIdx.y >= 16 -> V written TRANSPOSED into Vtg[b][h][d][s]
// ---------------------------------------------------------------------------
template <typename CT, bool FUSED>
__global__ __launch_bounds__(256) void gemm128(
    const __hip_bfloat16* __restrict__ A,
    const __hip_bfloat16* __restrict__ B,
    CT* __restrict__ C, int K, int ldc,
    __hip_bfloat16* __restrict__ Vtg) {
    __shared__ __hip_bfloat16 As[128 * 32];
    __shared__ __hip_bfloat16 Bs[128 * 32];
    const int t    = threadIdx.x;
    const int wave = t >> 6;
    const int lane = t & 63;
    const int quad = lane >> 4;
    const int l16  = lane & 15;
    const int wy = wave >> 1, wx = wave & 1;
    const int m0 = blockIdx.x * 128, n0 = blockIdx.y * 128;

    const int r0 = wave * 32 + (lane >> 2);
    const int c0 = (lane & 3) * 8;
    const __hip_bfloat16* Ag0 = A + (size_t)(m0 + r0) * K + c0;
    const __hip_bfloat16* Ag1 = Ag0 + (size_t)16 * K;
    const __hip_bfloat16* Bg0 = B + (size_t)(n0 + r0) * K + c0;
    const __hip_bfloat16* Bg1 = Bg0 + (size_t)16 * K;
    __hip_bfloat16* lA0 = &As[r0 * 32 + c0];
    __hip_bfloat16* lA1 = &As[(r0 + 16) * 32 + c0];
    __hip_bfloat16* lB0 = &Bs[r0 * 32 + c0];
    __hip_bfloat16* lB1 = &Bs[(r0 + 16) * 32 + c0];

    f32x4 acc[4][4];
#pragma unroll
    for (int i = 0; i < 4; i++)
#pragma unroll
        for (int j = 0; j < 4; j++) acc[i][j] = (f32x4){0.f, 0.f, 0.f, 0.f};

    for (int k0 = 0; k0 < K; k0 += 32) {
        __syncthreads();
        gload_lds16(Ag0 + k0, lA0);
        gload_lds16(Ag1 + k0, lA1);
        gload_lds16(Bg0 + k0, lB0);
        gload_lds16(Bg1 + k0, lB1);
        __syncthreads();

        bf16x8 af[4], bfr[4];
#pragma unroll
        for (int rb = 0; rb < 4; rb++)
            af[rb] = *(const bf16x8*)&As[(wy * 64 + rb * 16 + l16) * 32 + quad * 8];
#pragma unroll
        for (int cb = 0; cb < 4; cb++)
            bfr[cb] = *(const bf16x8*)&Bs[(wx * 64 + cb * 16 + l16) * 32 + quad * 8];
#pragma unroll
        for (int rb = 0; rb < 4; rb++)
#pragma unroll
            for (int cb = 0; cb < 4; cb++)
                acc[rb][cb] = __builtin_amdgcn_mfma_f32_16x16x32_bf16(
                    af[rb], bfr[cb], acc[rb][cb], 0, 0, 0);
    }

    if (!FUSED || blockIdx.y < 16) {
#pragma unroll
        for (int rb = 0; rb < 4; rb++)
#pragma unroll
            for (int r = 0; r < 4; r++) {
                size_t ro = (size_t)(m0 + wy * 64 + rb * 16 + quad * 4 + r) * ldc;
#pragma unroll
                for (int cb = 0; cb < 4; cb++)
                    store_c(&C[ro + n0 + wx * 64 + cb * 16 + l16], acc[rb][cb][r]);
            }
    } else {
#pragma unroll
        for (int rb = 0; rb < 4; rb++) {
            int row0 = m0 + wy * 64 + rb * 16 + quad * 4;
            int bb = row0 >> 11, ss = row0 & (SEQ_LEN - 1);
#pragma unroll
            for (int cb = 0; cb < 4; cb++) {
                int vcol = n0 + wx * 64 + cb * 16 + l16 - 2048;
                int hh = vcol >> 6, dd = vcol & 63;
                ushort4 u;
                u.x = (unsigned short)f2b(acc[rb][cb][0]);
                u.y = (unsigned short)f2b(acc[rb][cb][1]);
                u.z = (unsigned short)f2b(acc[rb][cb][2]);
                u.w = (unsigned short)f2b(acc[rb][cb][3]);
                *(ushort4*)(Vtg + ((size_t)(bb * NH + hh) * HD + dd) * SEQ_LEN + ss) = u;
            }
        }
    }
}

// ---------------------------------------------------------------------------
// RoPE in-place on QKb [NR][2048]; Q heads scaled by 0.125.
// ---------------------------------------------------------------------------
__global__ __launch_bounds__(256) void rope_kernel(
    __hip_bfloat16* __restrict__ QK, const int* __restrict__ pos) {
    int idx = blockIdx.x * 256 + threadIdx.x;
    int row  = idx >> 8;
    int tcol = idx & 255;
    int col0 = tcol * 8;
    int head = col0 >> 6;
    int i0   = (col0 & 63) >> 1;
    float p  = (float)pos[row & (SEQ_LEN - 1)];
    float scale = (head < NH) ? 0.125f : 1.0f;
    __hip_bfloat16* ptr = QK + (size_t)row * LDQK + col0;
    bf16x8 v = *(const bf16x8*)ptr;
    bf16x8 o;
#pragma unroll
    for (int k = 0; k < 4; k++) {
        float fr = __expf(-(float)(2 * (i0 + k)) * (9.210340371976184f / 64.0f));
        float ang = p * fr;
        float sn = sinf(ang), cs = cosf(ang);
        float e  = b2f(v[2 * k]);
        float od = b2f(v[2 * k + 1]);
        o[2 * k]     = f2b((e * cs - od * sn) * scale);
        o[2 * k + 1] = f2b((e * sn + od * cs) * scale);
    }
    *(bf16x8*)ptr = o;
}

// ---------------------------------------------------------------------------
// Causal MFMA flash attention, CONSTANT-WORK blocks (diagonal pairing).
// Block = 512 thr (8 waves) = one (b, h, q-tile PAIR): waves 0-3 process
// q-tile qt_a = pairIdx (128 rows), waves 4-7 process qt_b = 15 - pairIdx.
// Grid is FLAT 256 with XCD co-location decode: all 8 pair-blocks of one
// (b,h) share blockIdx%8 -> same XCD -> K/V (512 KB) stays L2-resident.
// Per wave: 32 q rows, fixed-max softmax, per-wave causal trip bound,
// K/V frags REGISTER DOUBLE-BUFFERED (prefetch tile kt+1 while computing
// tile kt -> hides global-load latency under the QK/exp/LDS/PV chain),
// P via wave-private LDS C->A roundtrip. Zero __syncthreads.
// ---------------------------------------------------------------------------
__global__ __launch_bounds__(512) void attn_kernel(
    const __hip_bfloat16* __restrict__ QK,
    const __hip_bfloat16* __restrict__ Vtg,
    __hip_bfloat16* __restrict__ O) {
    __shared__ short Ps[256][72];  // [q_local][key], per-wave 32-row regions

    const int t    = threadIdx.x;
    const int wave = t >> 6;        // 0..7
    const int team = wave >> 2;     // 0: qt_a, 1: qt_b
    const int w4   = wave & 3;
    const int lane = t & 63;
    const int quad = lane >> 4;
    const int l16  = lane & 15;
    // XCD co-location: id = pair*32 + hb  ->  id % 8 == hb % 8 (const per (b,h))
    const int pairIdx = blockIdx.x >> 5;  // 0..7
    const int hb      = blockIdx.x & 31;
    const int h       = hb & 15;
    const int b       = hb >> 4;

    const int qt   = team == 0 ? pairIdx : 15 - pairIdx;
    const int row0 = qt * 128 + w4 * 32;

    bf16x8 qf[2][2];
#pragma unroll
    for (int g = 0; g < 2; g++) {
        const __hip_bfloat16* qp =
            QK + (size_t)(b * SEQ_LEN + row0 + g * 16 + l16) * LDQK + h * HD + quad * 8;
        qf[g][0] = *(const bf16x8*)qp;
        qf[g][1] = *(const bf16x8*)(qp + 32);
    }

    f32x4 o[2][4];
    float l_p[2][4];
#pragma unroll
    for (int g = 0; g < 2; g++)
#pragma unroll
        for (int r = 0; r < 4; r++) {
            o[g][r] = (f32x4){0.f, 0.f, 0.f, 0.f};
            l_p[g][r] = 0.f;
        }

    const __hip_bfloat16* kbase = QK + (size_t)(b * SEQ_LEN) * LDQK + DM + h * HD;
    const __hip_bfloat16* vbase = Vtg + (size_t)((b * NH + h) * HD) * SEQ_LEN;

    const int ktmax = (row0 + 31) >> 6;  // per-wave causal bound

// ---- load K/V fragments for tile KT into named register buffers ----
#define LOADT(KT, KF, VF)                                                        \
    {                                                                            \
        _Pragma("unroll")                                                        \
        for (int kb = 0; kb < 4; kb++) {                                         \
            const __hip_bfloat16* kp =                                           \
                kbase + (size_t)((KT) * 64 + kb * 16 + l16) * LDQK + quad * 8;   \
            KF[kb][0] = *(const bf16x8*)kp;                                      \
            KF[kb][1] = *(const bf16x8*)(kp + 32);                               \
        }                                                                        \
        _Pragma("unroll")                                                        \
        for (int db = 0; db < 4; db++) {                                         \
            const __hip_bfloat16* vp =                                           \
                vbase + (size_t)(db * 16 + l16) * SEQ_LEN + (KT) * 64 + quad * 8;\
            VF[db][0] = *(const bf16x8*)vp;                                      \
            VF[db][1] = *(const bf16x8*)(vp + 32);                               \
        }                                                                        \
    }

// ---- one K-tile trip: S = QK^T, mask, p=exp(s), stage P, O += P V ----
#define TRIP(KT, KF, VF)                                                         \
    {                                                                            \
        f32x4 s[2][4];                                                           \
        _Pragma("unroll")                                                        \
        for (int g = 0; g < 2; g++)                                              \
            _Pragma("unroll")                                                    \
            for (int kb = 0; kb < 4; kb++) {                                     \
                f32x4 z = {0.f, 0.f, 0.f, 0.f};                                  \
                z = __builtin_amdgcn_mfma_f32_16x16x32_bf16(qf[g][0], KF[kb][0], z, 0, 0, 0); \
                z = __builtin_amdgcn_mfma_f32_16x16x32_bf16(qf[g][1], KF[kb][1], z, 0, 0, 0); \
                s[g][kb] = z;                                                    \
            }                                                                    \
        if ((KT) == ktmax) { /* causal mask on the diagonal tile */              \
            _Pragma("unroll")                                                    \
            for (int g = 0; g < 2; g++)                                          \
                _Pragma("unroll")                                                \
                for (int kb = 0; kb < 4; kb++) {                                 \
                    int key = (KT) * 64 + kb * 16 + l16;                         \
                    _Pragma("unroll")                                            \
                    for (int r = 0; r < 4; r++) {                                \
                        int rowg = row0 + g * 16 + quad * 4 + r;                 \
                        if (key > rowg) s[g][kb][r] = -1e30f;                    \
                    }                                                            \
                }                                                                \
        }                                                                        \
        _Pragma("unroll")                                                        \
        for (int g = 0; g < 2; g++)                                              \
            _Pragma("unroll")                                                    \
            for (int r = 0; r < 4; r++) {                                        \
                float p0 = __expf(s[g][0][r]);                                   \
                float p1 = __expf(s[g][1][r]);                                   \
                float p2 = __expf(s[g][2][r]);                                   \
                float p3 = __expf(s[g][3][r]);                                   \
                l_p[g][r] += (p0 + p1) + (p2 + p3);                              \
                int prow = wave * 32 + g * 16 + quad * 4 + r;                    \
                Ps[prow][ 0 + l16] = f2b(p0);                                    \
                Ps[prow][16 + l16] = f2b(p1);                                    \
                Ps[prow][32 + l16] = f2b(p2);                                    \
                Ps[prow][48 + l16] = f2b(p3);                                    \
            }                                                                    \
        _Pragma("unroll")                                                        \
        for (int g = 0; g < 2; g++) {                                            \
            bf16x8 pf0 = *(const bf16x8*)&Ps[wave * 32 + g * 16 + l16][quad * 8];      \
            bf16x8 pf1 = *(const bf16x8*)&Ps[wave * 32 + g * 16 + l16][32 + quad * 8]; \
            _Pragma("unroll")                                                    \
            for (int db = 0; db < 4; db++) {                                     \
                o[g][db] = __builtin_amdgcn_mfma_f32_16x16x32_bf16(pf0, VF[db][0], o[g][db], 0, 0, 0); \
                o[g][db] = __builtin_amdgcn_mfma_f32_16x16x32_bf16(pf1, VF[db][1], o[g][db], 0, 0, 0); \
            }                                                                    \
        }                                                                        \
    }

    // Register double-buffer: prefetch tile kt+1 (no deps) BEFORE computing
    // tile kt, so global-load latency hides under the QK->exp->LDS->PV chain.
    // Hand-unrolled 2-step rotation with NAMED buffers (no runtime indexing).
    bf16x8 kfA[4][2], vfA[4][2], kfB[4][2], vfB[4][2];
    LOADT(0, kfA, vfA);
    int kt = 0;
    while (true) {
        if (kt < ktmax) LOADT(kt + 1, kfB, vfB);
        TRIP(kt, kfA, vfA);
        if (kt >= ktmax) break;
        ++kt;
        if (kt < ktmax) LOADT(kt + 1, kfA, vfA);
        TRIP(kt, kfB, vfB);
        if (kt >= ktmax) break;
        ++kt;
    }
#undef LOADT
#undef TRIP

    // ---- epilogue: reduce l across the 16-lane row group, normalize ----
#pragma unroll
    for (int g = 0; g < 2; g++)
#pragma unroll
        for (int r = 0; r < 4; r++) {
            float rs = l_p[g][r];
            rs += __shfl_xor(rs, 1);
            rs += __shfl_xor(rs, 2);
            rs += __shfl_xor(rs, 4);
            rs += __shfl_xor(rs, 8);
            float inv = 1.0f / rs;
            size_t ro = (size_t)(b * SEQ_LEN + row0 + g * 16 + quad * 4 + r) * DM + h * HD;
            O[ro +  0 + l16] = __float2bfloat16(o[g][0][r] * inv);
            O[ro + 16 + l16] = __float2bfloat16(o[g][1][r] * inv);
            O[ro + 32 + l16] = __float2bfloat16(o[g][2][r] * inv);
            O[ro + 48 + l16] = __float2bfloat16(o[g][3][r] * inv);
        }
}

// ---------------------------------------------------------------------------
// Workspace (40 MiB of 48):
//   [0,8)    xb [4096x1024] bf16, reused as Ab (attn output)
//   [8,14)   Wqkvb [3072x1024] bf16
//   [14,16)  Wob [1024x1024] bf16
//   [16,32)  QKb [4096x2048] bf16 (Q roped+scaled, K roped)
//   [32,40)  Vtg [2][16][64][2048] bf16
// ---------------------------------------------------------------------------
extern "C" void kernel_launch(void* const* d_in, const int* in_sizes, int n_in,
                              void* d_out, int out_size, void* d_ws, size_t ws_size,
                              hipStream_t stream) {
    const float* x  = (const float*)d_in[0];
    const float* Wq = (const float*)d_in[1];
    const float* Wk = (const float*)d_in[2];
    const float* Wv = (const float*)d_in[3];
    const float* Wo = (const float*)d_in[4];
    const int* pos = (const int*)d_in[6];
    float* out = (float*)d_out;

    char* w = (char*)d_ws;
    const size_t MiB = 1024 * 1024;
    __hip_bfloat16* xb    = (__hip_bfloat16*)(w + 0 * MiB);
    __hip_bfloat16* Ab    = (__hip_bfloat16*)(w + 0 * MiB);  // reuse after QKV gemm
    __hip_bfloat16* Wqkvb = (__hip_bfloat16*)(w + 8 * MiB);
    __hip_bfloat16* Wob   = (__hip_bfloat16*)(w + 14 * MiB);
    __hip_bfloat16* QKb   = (__hip_bfloat16*)(w + 16 * MiB);
    __hip_bfloat16* Vtg   = (__hip_bfloat16*)(w + 32 * MiB);

    cvt_all<<<8192, 256, 0, stream>>>(x, Wq, Wk, Wv, Wo, xb, Wqkvb, Wob);

    gemm128<__hip_bfloat16, true><<<dim3(NR / 128, NQKV / 128), 256, 0, stream>>>(
        xb, Wqkvb, QKb, DM, LDQK, Vtg);

    rope_kernel<<<NR * LDQK / 8 / 256, 256, 0, stream>>>(QKb, pos);

    attn_kernel<<<256, 512, 0, stream>>>(QKb, Vtg, Ab);

    gemm128<float, false><<<dim3(NR / 128, DM / 128), 256, 0, stream>>>(
        Ab, Wob, out, DM, DM, nullptr);
}

// Round 2
// 211.836 us; speedup vs baseline: 1.2492x; 1.2492x over previous
//
#include <hip/hip_runtime.h>
#include <hip/hip_bf16.h>

#define SEQ_LEN 2048
#define NBATCH 2
#define DM 1024
#define NH 16
#define HD 64
#define NR (NBATCH * SEQ_LEN)  // 4096 rows
#define NQKV (3 * DM)          // 3072 fused QKV cols
#define LDQK 2048              // QK buffer leading dim (Q cols 0..1023, K 1024..2047)

typedef __attribute__((ext_vector_type(8))) short bf16x8;
typedef __attribute__((ext_vector_type(4))) float f32x4;

__device__ __forceinline__ short f2b(float f) {
    __hip_bfloat16 h = __float2bfloat16(f);
    return *reinterpret_cast<short*>(&h);
}
__device__ __forceinline__ float b2f(short s) {
    union { unsigned u; float f; } x;
    x.u = ((unsigned)(unsigned short)s) << 16;
    return x.f;
}

// async global->LDS 16B copy
__device__ __forceinline__ void gload_lds16(const void* g, void* l) {
    __builtin_amdgcn_global_load_lds(
        (const __attribute__((address_space(1))) unsigned int*)g,
        (__attribute__((address_space(3))) unsigned int*)l, 16, 0, 0);
}

// ---------------------------------------------------------------------------
// Fused fp32->bf16 conversion for all 5 inputs in one launch.
// ---------------------------------------------------------------------------
__global__ __launch_bounds__(256) void cvt_all(
    const float* __restrict__ x,  const float* __restrict__ wq,
    const float* __restrict__ wk, const float* __restrict__ wv,
    const float* __restrict__ wo,
    __hip_bfloat16* __restrict__ xb, __hip_bfloat16* __restrict__ wqkvb,
    __hip_bfloat16* __restrict__ wob) {
    int id = blockIdx.x;
    const float* src; __hip_bfloat16* dst;
    if (id < 4096) { src = x + (size_t)id * 1024; dst = xb + (size_t)id * 1024; }
    else {
        int k = id - 4096, seg = k >> 10;
        size_t off = (size_t)(k & 1023) * 1024;
        if      (seg == 0) { src = wq + off; dst = wqkvb + off; }
        else if (seg == 1) { src = wk + off; dst = wqkvb + (1u << 20) + off; }
        else if (seg == 2) { src = wv + off; dst = wqkvb + (2u << 20) + off; }
        else               { src = wo + off; dst = wob + off; }
    }
    int i = threadIdx.x * 4;
    float4 v = *(const float4*)(src + i);
    dst[i + 0] = __float2bfloat16(v.x);
    dst[i + 1] = __float2bfloat16(v.y);
    dst[i + 2] = __float2bfloat16(v.z);
    dst[i + 3] = __float2bfloat16(v.w);
}

__device__ __forceinline__ void store_c(float* p, float v) { *p = v; }
__device__ __forceinline__ void store_c(__hip_bfloat16* p, float v) {
    *p = __float2bfloat16(v);
}

// ---------------------------------------------------------------------------
// m97-style GEMM: C[M,N] = A[M,K] @ B[N,K]^T, 128x128 tile, BK=32, 4 waves,
// global_load_lds width-16 staging. FUSED=true (QKV projection):
//   blockIdx.y < 16 -> bf16 store into QKb (ldc = 2048)
//   blockIdx.y >= 16 -> V written TRANSPOSED into Vtg[b][h][d][s]
// ---------------------------------------------------------------------------
template <typename CT, bool FUSED>
__global__ __launch_bounds__(256) void gemm128(
    const __hip_bfloat16* __restrict__ A,
    const __hip_bfloat16* __restrict__ B,
    CT* __restrict__ C, int K, int ldc,
    __hip_bfloat16* __restrict__ Vtg) {
    __shared__ __hip_bfloat16 As[128 * 32];
    __shared__ __hip_bfloat16 Bs[128 * 32];
    const int t    = threadIdx.x;
    const int wave = t >> 6;
    const int lane = t & 63;
    const int quad = lane >> 4;
    const int l16  = lane & 15;
    const int wy = wave >> 1, wx = wave & 1;
    const int m0 = blockIdx.x * 128, n0 = blockIdx.y * 128;

    const int r0 = wave * 32 + (lane >> 2);
    const int c0 = (lane & 3) * 8;
    const __hip_bfloat16* Ag0 = A + (size_t)(m0 + r0) * K + c0;
    const __hip_bfloat16* Ag1 = Ag0 + (size_t)16 * K;
    const __hip_bfloat16* Bg0 = B + (size_t)(n0 + r0) * K + c0;
    const __hip_bfloat16* Bg1 = Bg0 + (size_t)16 * K;
    __hip_bfloat16* lA0 = &As[r0 * 32 + c0];
    __hip_bfloat16* lA1 = &As[(r0 + 16) * 32 + c0];
    __hip_bfloat16* lB0 = &Bs[r0 * 32 + c0];
    __hip_bfloat16* lB1 = &Bs[(r0 + 16) * 32 + c0];

    f32x4 acc[4][4];
#pragma unroll
    for (int i = 0; i < 4; i++)
#pragma unroll
        for (int j = 0; j < 4; j++) acc[i][j] = (f32x4){0.f, 0.f, 0.f, 0.f};

    for (int k0 = 0; k0 < K; k0 += 32) {
        __syncthreads();
        gload_lds16(Ag0 + k0, lA0);
        gload_lds16(Ag1 + k0, lA1);
        gload_lds16(Bg0 + k0, lB0);
        gload_lds16(Bg1 + k0, lB1);
        __syncthreads();

        bf16x8 af[4], bfr[4];
#pragma unroll
        for (int rb = 0; rb < 4; rb++)
            af[rb] = *(const bf16x8*)&As[(wy * 64 + rb * 16 + l16) * 32 + quad * 8];
#pragma unroll
        for (int cb = 0; cb < 4; cb++)
            bfr[cb] = *(const bf16x8*)&Bs[(wx * 64 + cb * 16 + l16) * 32 + quad * 8];
#pragma unroll
        for (int rb = 0; rb < 4; rb++)
#pragma unroll
            for (int cb = 0; cb < 4; cb++)
                acc[rb][cb] = __builtin_amdgcn_mfma_f32_16x16x32_bf16(
                    af[rb], bfr[cb], acc[rb][cb], 0, 0, 0);
    }

    if (!FUSED || blockIdx.y < 16) {
#pragma unroll
        for (int rb = 0; rb < 4; rb++)
#pragma unroll
            for (int r = 0; r < 4; r++) {
                size_t ro = (size_t)(m0 + wy * 64 + rb * 16 + quad * 4 + r) * ldc;
#pragma unroll
                for (int cb = 0; cb < 4; cb++)
                    store_c(&C[ro + n0 + wx * 64 + cb * 16 + l16], acc[rb][cb][r]);
            }
    } else {
#pragma unroll
        for (int rb = 0; rb < 4; rb++) {
            int row0 = m0 + wy * 64 + rb * 16 + quad * 4;
            int bb = row0 >> 11, ss = row0 & (SEQ_LEN - 1);
#pragma unroll
            for (int cb = 0; cb < 4; cb++) {
                int vcol = n0 + wx * 64 + cb * 16 + l16 - 2048;
                int hh = vcol >> 6, dd = vcol & 63;
                ushort4 u;
                u.x = (unsigned short)f2b(acc[rb][cb][0]);
                u.y = (unsigned short)f2b(acc[rb][cb][1]);
                u.z = (unsigned short)f2b(acc[rb][cb][2]);
                u.w = (unsigned short)f2b(acc[rb][cb][3]);
                *(ushort4*)(Vtg + ((size_t)(bb * NH + hh) * HD + dd) * SEQ_LEN + ss) = u;
            }
        }
    }
}

// ---------------------------------------------------------------------------
// RoPE in-place on QKb [NR][2048]; Q heads scaled by 0.125.
// ---------------------------------------------------------------------------
__global__ __launch_bounds__(256) void rope_kernel(
    __hip_bfloat16* __restrict__ QK, const int* __restrict__ pos) {
    int idx = blockIdx.x * 256 + threadIdx.x;
    int row  = idx >> 8;
    int tcol = idx & 255;
    int col0 = tcol * 8;
    int head = col0 >> 6;
    int i0   = (col0 & 63) >> 1;
    float p  = (float)pos[row & (SEQ_LEN - 1)];
    float scale = (head < NH) ? 0.125f : 1.0f;
    __hip_bfloat16* ptr = QK + (size_t)row * LDQK + col0;
    bf16x8 v = *(const bf16x8*)ptr;
    bf16x8 o;
#pragma unroll
    for (int k = 0; k < 4; k++) {
        float fr = __expf(-(float)(2 * (i0 + k)) * (9.210340371976184f / 64.0f));
        float ang = p * fr;
        float sn = sinf(ang), cs = cosf(ang);
        float e  = b2f(v[2 * k]);
        float od = b2f(v[2 * k + 1]);
        o[2 * k]     = f2b((e * cs - od * sn) * scale);
        o[2 * k + 1] = f2b((e * sn + od * cs) * scale);
    }
    *(bf16x8*)ptr = o;
}

// ---------------------------------------------------------------------------
// Causal MFMA flash attention, SEQUENTIAL-PAIR constant-work blocks.
// Block = 512 thr (8 waves) processes q-tile (15-pairIdx) with ALL 8 waves
// (16 q-rows each), then q-tile pairIdx. Total trips = 34 for every block
// -> constant work AND uniform trip counts -> block-wide __syncthreads legal.
// K/V tiles are staged in LDS via async global_load_lds (zero VGPR cost),
// 2-phase double-buffered: stage tile kt+1 right after the barrier, compute
// tile kt from LDS, next barrier drains. T2 XOR-swizzle on the LDS tiles
// (applied on the GLOBAL SOURCE address + the ds_read address, since
// global_load_lds writes linearly) kills the 16-way bank conflict a
// row-stride-128B tile would have. Grid flat 256 with XCD co-location
// decode: all 8 pair-blocks of one (b,h) share blockIdx%8 -> same XCD ->
// K/V stays L2-resident (proven: FETCH 55->17 MB).
// ---------------------------------------------------------------------------
__global__ __launch_bounds__(512) void attn_kernel(
    const __hip_bfloat16* __restrict__ QK,
    const __hip_bfloat16* __restrict__ Vtg,
    __hip_bfloat16* __restrict__ O) {
    __shared__ __hip_bfloat16 Ks[2][64 * 64];  // [buf][row][col] XOR-swizzled
    __shared__ __hip_bfloat16 Vs[2][64 * 64];  // [buf][d][key]   XOR-swizzled
    __shared__ short Ps[128][72];              // [q_local][key], wave-private

    const int t    = threadIdx.x;
    const int wave = t >> 6;        // 0..7
    const int lane = t & 63;
    const int quad = lane >> 4;
    const int l16  = lane & 15;
    // XCD co-location: id = pair*32 + hb  ->  id % 8 == hb % 8 (const per (b,h))
    const int pairIdx = blockIdx.x >> 5;  // 0..7
    const int hb      = blockIdx.x & 31;
    const int h       = hb & 15;
    const int b       = hb >> 4;

    // staging decomposition: thread t -> tile row sr (0..63), 16B col-block
    // (t&7); source col-block pre-swizzled so the linear LDS write lands the
    // swizzled layout: slot (r, cb) holds global block cb ^ (r&7).
    const int sr  = t >> 3;
    const int scs = (t & 7) ^ (sr & 7);

    const __hip_bfloat16* kbase = QK + (size_t)(b * SEQ_LEN) * LDQK + DM + h * HD;
    const __hip_bfloat16* vbase = Vtg + (size_t)((b * NH + h) * HD) * SEQ_LEN;

#define STAGE(BUF, KT)                                                          \
    {                                                                           \
        gload_lds16(kbase + (size_t)((KT) * 64 + sr) * LDQK + scs * 8,          \
                    (char*)&Ks[BUF][0] + t * 16);                               \
        gload_lds16(vbase + (size_t)sr * SEQ_LEN + (KT) * 64 + scs * 8,         \
                    (char*)&Vs[BUF][0] + t * 16);                               \
    }

// swizzled 16B fragment read: row RR, col-block G (8 bf16 per block)
#define LDS_FRAG(BASE, RR, G)                                                   \
    (*(const bf16x8*)((const char*)(BASE) + (RR) * 128 + ((((G) ^ ((RR) & 7))) << 4)))

// one K-tile trip: S = QK^T, mask, p=exp(s), stage P, O += P V
#define TRIP(BUF, KT)                                                           \
    {                                                                           \
        bf16x8 kf[4][2];                                                        \
        _Pragma("unroll") for (int kb = 0; kb < 4; kb++) {                      \
            int rr = kb * 16 + l16;                                             \
            kf[kb][0] = LDS_FRAG(Ks[BUF], rr, quad);                            \
            kf[kb][1] = LDS_FRAG(Ks[BUF], rr, quad + 4);                        \
        }                                                                       \
        f32x4 s[4];                                                             \
        _Pragma("unroll") for (int kb = 0; kb < 4; kb++) {                      \
            f32x4 z = {0.f, 0.f, 0.f, 0.f};                                     \
            z = __builtin_amdgcn_mfma_f32_16x16x32_bf16(qf0, kf[kb][0], z, 0, 0, 0); \
            z = __builtin_amdgcn_mfma_f32_16x16x32_bf16(qf1, kf[kb][1], z, 0, 0, 0); \
            s[kb] = z;                                                          \
        }                                                                       \
        if ((KT) == ktd) { /* causal mask on the diagonal tile */               \
            _Pragma("unroll") for (int kb = 0; kb < 4; kb++) {                  \
                int key = (KT) * 64 + kb * 16 + l16;                            \
                _Pragma("unroll") for (int r = 0; r < 4; r++) {                 \
                    int rowg = row0 + quad * 4 + r;                             \
                    if (key > rowg) s[kb][r] = -1e30f;                          \
                }                                                               \
            }                                                                   \
        }                                                                       \
        _Pragma("unroll") for (int r = 0; r < 4; r++) {                         \
            float p0 = __expf(s[0][r]);                                         \
            float p1 = __expf(s[1][r]);                                         \
            float p2 = __expf(s[2][r]);                                         \
            float p3 = __expf(s[3][r]);                                         \
            l_p[r] += (p0 + p1) + (p2 + p3);                                    \
            int prow = wave * 16 + quad * 4 + r;                                \
            Ps[prow][ 0 + l16] = f2b(p0);                                       \
            Ps[prow][16 + l16] = f2b(p1);                                       \
            Ps[prow][32 + l16] = f2b(p2);                                       \
            Ps[prow][48 + l16] = f2b(p3);                                       \
        }                                                                       \
        bf16x8 pf0 = *(const bf16x8*)&Ps[wave * 16 + l16][quad * 8];            \
        bf16x8 pf1 = *(const bf16x8*)&Ps[wave * 16 + l16][32 + quad * 8];       \
        _Pragma("unroll") for (int db = 0; db < 4; db++) {                      \
            int rr = db * 16 + l16;                                             \
            bf16x8 vf0 = LDS_FRAG(Vs[BUF], rr, quad);                           \
            bf16x8 vf1 = LDS_FRAG(Vs[BUF], rr, quad + 4);                       \
            o[db] = __builtin_amdgcn_mfma_f32_16x16x32_bf16(pf0, vf0, o[db], 0, 0, 0); \
            o[db] = __builtin_amdgcn_mfma_f32_16x16x32_bf16(pf1, vf1, o[db], 0, 0, 0); \
        }                                                                       \
    }

#define FINALIZE()                                                              \
    {                                                                           \
        _Pragma("unroll") for (int r = 0; r < 4; r++) {                         \
            float rs = l_p[r];                                                  \
            rs += __shfl_xor(rs, 1);                                            \
            rs += __shfl_xor(rs, 2);                                            \
            rs += __shfl_xor(rs, 4);                                            \
            rs += __shfl_xor(rs, 8);                                            \
            float inv = 1.0f / rs;                                              \
            size_t ro = (size_t)(b * SEQ_LEN + row0 + quad * 4 + r) * DM + h * HD; \
            O[ro +  0 + l16] = __float2bfloat16(o[0][r] * inv);                 \
            O[ro + 16 + l16] = __float2bfloat16(o[1][r] * inv);                 \
            O[ro + 32 + l16] = __float2bfloat16(o[2][r] * inv);                 \
            O[ro + 48 + l16] = __float2bfloat16(o[3][r] * inv);                 \
        }                                                                       \
    }

    const int qtB = 15 - pairIdx;     // phase-0 q-tile (2*qtB+2 trips)
    const int n0t = 2 * qtB + 2;      // phase-0 trip count; total is always 34

    int row0 = qtB * 128 + wave * 16; // this wave's first q row
    int ktd  = row0 >> 6;             // diagonal (= last useful) K-tile
    bf16x8 qf0, qf1;
    {
        const __hip_bfloat16* qp =
            QK + (size_t)(b * SEQ_LEN + row0 + l16) * LDQK + h * HD + quad * 8;
        qf0 = *(const bf16x8*)qp;
        qf1 = *(const bf16x8*)(qp + 32);
    }
    f32x4 o[4];
    float l_p[4];
#pragma unroll
    for (int r = 0; r < 4; r++) { o[r] = (f32x4){0.f, 0.f, 0.f, 0.f}; l_p[r] = 0.f; }

    STAGE(0, 0);
    for (int i = 0; i < 34; ++i) {
        const int buf = i & 1;
        __syncthreads();  // staging of buf complete; buf^1 free for reuse
        if (i + 1 < 34) {
            int inext = i + 1;
            int ktn = (inext < n0t) ? inext : inext - n0t;
            STAGE(buf ^ 1, ktn);  // async; drains at NEXT barrier, hides under compute
        }
        const int kt = (i < n0t) ? i : i - n0t;
        if (kt <= ktd) TRIP(buf, kt);  // wave-uniform guard, no barrier inside
        if (i == n0t - 1) {
            FINALIZE();  // phase 0 output
            row0 = pairIdx * 128 + wave * 16;
            ktd  = row0 >> 6;
            const __hip_bfloat16* qp =
                QK + (size_t)(b * SEQ_LEN + row0 + l16) * LDQK + h * HD + quad * 8;
            qf0 = *(const bf16x8*)qp;
            qf1 = *(const bf16x8*)(qp + 32);
#pragma unroll
            for (int r = 0; r < 4; r++) { o[r] = (f32x4){0.f, 0.f, 0.f, 0.f}; l_p[r] = 0.f; }
        }
    }
    FINALIZE();
#undef STAGE
#undef LDS_FRAG
#undef TRIP
#undef FINALIZE
}

// ---------------------------------------------------------------------------
// Workspace (40 MiB of 48):
//   [0,8)    xb [4096x1024] bf16, reused as Ab (attn output)
//   [8,14)   Wqkvb [3072x1024] bf16
//   [14,16)  Wob [1024x1024] bf16
//   [16,32)  QKb [4096x2048] bf16 (Q roped+scaled, K roped)
//   [32,40)  Vtg [2][16][64][2048] bf16
// ---------------------------------------------------------------------------
extern "C" void kernel_launch(void* const* d_in, const int* in_sizes, int n_in,
                              void* d_out, int out_size, void* d_ws, size_t ws_size,
                              hipStream_t stream) {
    const float* x  = (const float*)d_in[0];
    const float* Wq = (const float*)d_in[1];
    const float* Wk = (const float*)d_in[2];
    const float* Wv = (const float*)d_in[3];
    const float* Wo = (const float*)d_in[4];
    const int* pos = (const int*)d_in[6];
    float* out = (float*)d_out;

    char* w = (char*)d_ws;
    const size_t MiB = 1024 * 1024;
    __hip_bfloat16* xb    = (__hip_bfloat16*)(w + 0 * MiB);
    __hip_bfloat16* Ab    = (__hip_bfloat16*)(w + 0 * MiB);  // reuse after QKV gemm
    __hip_bfloat16* Wqkvb = (__hip_bfloat16*)(w + 8 * MiB);
    __hip_bfloat16* Wob   = (__hip_bfloat16*)(w + 14 * MiB);
    __hip_bfloat16* QKb   = (__hip_bfloat16*)(w + 16 * MiB);
    __hip_bfloat16* Vtg   = (__hip_bfloat16*)(w + 32 * MiB);

    cvt_all<<<8192, 256, 0, stream>>>(x, Wq, Wk, Wv, Wo, xb, Wqkvb, Wob);

    gemm128<__hip_bfloat16, true><<<dim3(NR / 128, NQKV / 128), 256, 0, stream>>>(
        xb, Wqkvb, QKb, DM, LDQK, Vtg);

    rope_kernel<<<NR * LDQK / 8 / 256, 256, 0, stream>>>(QKb, pos);

    attn_kernel<<<256, 512, 0, stream>>>(QKb, Vtg, Ab);

    gemm128<float, false><<<dim3(NR / 128, DM / 128), 256, 0, stream>>>(
        Ab, Wob, out, DM, DM, nullptr);
}

// Round 3
// 198.631 us; speedup vs baseline: 1.3322x; 1.0665x over previous
//
#include <hip/hip_runtime.h>
#include <hip/hip_bf16.h>

#define SEQ_LEN 2048
#define NBATCH 2
#define DM 1024
#define NH 16
#define HD 64
#define NR (NBATCH * SEQ_LEN)  // 4096 rows
#define NQKV (3 * DM)          // 3072 fused QKV cols
#define LDQK 2048              // QK buffer leading dim (Q cols 0..1023, K 1024..2047)

typedef __attribute__((ext_vector_type(8))) short bf16x8;
typedef __attribute__((ext_vector_type(4))) float f32x4;

__device__ __forceinline__ short f2b(float f) {
    __hip_bfloat16 h = __float2bfloat16(f);
    return *reinterpret_cast<short*>(&h);
}
__device__ __forceinline__ float b2f(short s) {
    union { unsigned u; float f; } x;
    x.u = ((unsigned)(unsigned short)s) << 16;
    return x.f;
}

// async global->LDS 16B copy
__device__ __forceinline__ void gload_lds16(const void* g, void* l) {
    __builtin_amdgcn_global_load_lds(
        (const __attribute__((address_space(1))) unsigned int*)g,
        (__attribute__((address_space(3))) unsigned int*)l, 16, 0, 0);
}

// ---------------------------------------------------------------------------
// Fused fp32->bf16 conversion for all 5 inputs in one launch.
// ---------------------------------------------------------------------------
__global__ __launch_bounds__(256) void cvt_all(
    const float* __restrict__ x,  const float* __restrict__ wq,
    const float* __restrict__ wk, const float* __restrict__ wv,
    const float* __restrict__ wo,
    __hip_bfloat16* __restrict__ xb, __hip_bfloat16* __restrict__ wqkvb,
    __hip_bfloat16* __restrict__ wob) {
    int id = blockIdx.x;
    const float* src; __hip_bfloat16* dst;
    if (id < 4096) { src = x + (size_t)id * 1024; dst = xb + (size_t)id * 1024; }
    else {
        int k = id - 4096, seg = k >> 10;
        size_t off = (size_t)(k & 1023) * 1024;
        if      (seg == 0) { src = wq + off; dst = wqkvb + off; }
        else if (seg == 1) { src = wk + off; dst = wqkvb + (1u << 20) + off; }
        else if (seg == 2) { src = wv + off; dst = wqkvb + (2u << 20) + off; }
        else               { src = wo + off; dst = wob + off; }
    }
    int i = threadIdx.x * 4;
    float4 v = *(const float4*)(src + i);
    dst[i + 0] = __float2bfloat16(v.x);
    dst[i + 1] = __float2bfloat16(v.y);
    dst[i + 2] = __float2bfloat16(v.z);
    dst[i + 3] = __float2bfloat16(v.w);
}

__device__ __forceinline__ void store_c(float* p, float v) { *p = v; }
__device__ __forceinline__ void store_c(__hip_bfloat16* p, float v) {
    *p = __float2bfloat16(v);
}

// ---------------------------------------------------------------------------
// m97-style GEMM: C[M,N] = A[M,K] @ B[N,K]^T, 128x128 tile, BK=32, 4 waves,
// global_load_lds width-16 staging. FUSED=true (QKV projection):
//   blockIdx.y < 16 -> RoPE applied in-register (partner via shfl_xor lane^1,
//                      Q scaled 0.125 folded into cos/sin), bf16 store to QKb
//   blockIdx.y >= 16 -> V written TRANSPOSED into Vtg[b][h][d][s]
// ---------------------------------------------------------------------------
template <typename CT, bool FUSED>
__global__ __launch_bounds__(256) void gemm128(
    const __hip_bfloat16* __restrict__ A,
    const __hip_bfloat16* __restrict__ B,
    CT* __restrict__ C, int K, int ldc,
    __hip_bfloat16* __restrict__ Vtg, const int* __restrict__ pos) {
    __shared__ __hip_bfloat16 As[128 * 32];
    __shared__ __hip_bfloat16 Bs[128 * 32];
    const int t    = threadIdx.x;
    const int wave = t >> 6;
    const int lane = t & 63;
    const int quad = lane >> 4;
    const int l16  = lane & 15;
    const int wy = wave >> 1, wx = wave & 1;
    const int m0 = blockIdx.x * 128, n0 = blockIdx.y * 128;

    const int r0 = wave * 32 + (lane >> 2);
    const int c0 = (lane & 3) * 8;
    const __hip_bfloat16* Ag0 = A + (size_t)(m0 + r0) * K + c0;
    const __hip_bfloat16* Ag1 = Ag0 + (size_t)16 * K;
    const __hip_bfloat16* Bg0 = B + (size_t)(n0 + r0) * K + c0;
    const __hip_bfloat16* Bg1 = Bg0 + (size_t)16 * K;
    __hip_bfloat16* lA0 = &As[r0 * 32 + c0];
    __hip_bfloat16* lA1 = &As[(r0 + 16) * 32 + c0];
    __hip_bfloat16* lB0 = &Bs[r0 * 32 + c0];
    __hip_bfloat16* lB1 = &Bs[(r0 + 16) * 32 + c0];

    f32x4 acc[4][4];
#pragma unroll
    for (int i = 0; i < 4; i++)
#pragma unroll
        for (int j = 0; j < 4; j++) acc[i][j] = (f32x4){0.f, 0.f, 0.f, 0.f};

    for (int k0 = 0; k0 < K; k0 += 32) {
        __syncthreads();
        gload_lds16(Ag0 + k0, lA0);
        gload_lds16(Ag1 + k0, lA1);
        gload_lds16(Bg0 + k0, lB0);
        gload_lds16(Bg1 + k0, lB1);
        __syncthreads();

        bf16x8 af[4], bfr[4];
#pragma unroll
        for (int rb = 0; rb < 4; rb++)
            af[rb] = *(const bf16x8*)&As[(wy * 64 + rb * 16 + l16) * 32 + quad * 8];
#pragma unroll
        for (int cb = 0; cb < 4; cb++)
            bfr[cb] = *(const bf16x8*)&Bs[(wx * 64 + cb * 16 + l16) * 32 + quad * 8];
#pragma unroll
        for (int rb = 0; rb < 4; rb++)
#pragma unroll
            for (int cb = 0; cb < 4; cb++)
                acc[rb][cb] = __builtin_amdgcn_mfma_f32_16x16x32_bf16(
                    af[rb], bfr[cb], acc[rb][cb], 0, 0, 0);
    }

    if (!FUSED || blockIdx.y < 16) {
        if constexpr (FUSED) {
            // ---- fused RoPE on Q/K columns (+0.125 scale on Q) ----
            const float sc = (blockIdx.y < 8) ? 0.125f : 1.0f;
            float fr[4];
#pragma unroll
            for (int cb = 0; cb < 4; cb++) {
                int i = ((cb * 16 + l16) & 63) >> 1;
                fr[cb] = __expf(-(float)(2 * i) * (9.210340371976184f / 64.0f));
            }
            const float par = (l16 & 1) ? 1.f : -1.f;  // odd lane: +pt*sn, even: -pt*sn
#pragma unroll
            for (int rb = 0; rb < 4; rb++)
#pragma unroll
                for (int r = 0; r < 4; r++) {
                    int row = m0 + wy * 64 + rb * 16 + quad * 4 + r;
                    float p = (float)pos[row & (SEQ_LEN - 1)];
#pragma unroll
                    for (int cb = 0; cb < 4; cb++) {
                        float sn, cs;
                        __sincosf(p * fr[cb], &sn, &cs);
                        float v  = acc[rb][cb][r];
                        float pt = __shfl_xor(v, 1);
                        acc[rb][cb][r] = (v * cs + par * pt * sn) * sc;
                    }
                }
        }
#pragma unroll
        for (int rb = 0; rb < 4; rb++)
#pragma unroll
            for (int r = 0; r < 4; r++) {
                size_t ro = (size_t)(m0 + wy * 64 + rb * 16 + quad * 4 + r) * ldc;
#pragma unroll
                for (int cb = 0; cb < 4; cb++)
                    store_c(&C[ro + n0 + wx * 64 + cb * 16 + l16], acc[rb][cb][r]);
            }
    } else {
#pragma unroll
        for (int rb = 0; rb < 4; rb++) {
            int row0 = m0 + wy * 64 + rb * 16 + quad * 4;
            int bb = row0 >> 11, ss = row0 & (SEQ_LEN - 1);
#pragma unroll
            for (int cb = 0; cb < 4; cb++) {
                int vcol = n0 + wx * 64 + cb * 16 + l16 - 2048;
                int hh = vcol >> 6, dd = vcol & 63;
                ushort4 u;
                u.x = (unsigned short)f2b(acc[rb][cb][0]);
                u.y = (unsigned short)f2b(acc[rb][cb][1]);
                u.z = (unsigned short)f2b(acc[rb][cb][2]);
                u.w = (unsigned short)f2b(acc[rb][cb][3]);
                *(ushort4*)(Vtg + ((size_t)(bb * NH + hh) * HD + dd) * SEQ_LEN + ss) = u;
            }
        }
    }
}

// ---------------------------------------------------------------------------
// Causal MFMA flash attention, small-block edition.
// Block = 256 thr (4 waves) = one 64-row q-tile of one (b,h); wave w owns
// rows w*16..w*16+15. Trips = qt+1 K-tiles (BLOCK-UNIFORM -> barriers legal,
// no divergence guards). Grid 1024, big-qt first (qt = 31 - id>>5) for load
// balance; id%8 = (b,h)%8 keeps all blocks of one (b,h) on one XCD (proven
// FETCH 55->12 MB). LDS 41 KB -> 3 independent blocks/CU = 12 waves/CU in
// DECORRELATED barrier domains: while one block drains its stage barrier,
// the other two compute -> hides the 2-phase stall that capped round 2.
// K/V async-staged to LDS (zero VGPR), XOR-swizzled via pre-swizzled global
// source + swizzled ds_read (both-sides rule). T5 setprio around MFMA.
// ---------------------------------------------------------------------------
__global__ __launch_bounds__(256) void attn_kernel(
    const __hip_bfloat16* __restrict__ QK,
    const __hip_bfloat16* __restrict__ Vtg,
    __hip_bfloat16* __restrict__ O) {
    __shared__ __hip_bfloat16 Ks[2][64 * 64];  // [buf][row][col] XOR-swizzled
    __shared__ __hip_bfloat16 Vs[2][64 * 64];  // [buf][d][key]   XOR-swizzled
    __shared__ short Ps[64][72];               // [q_local][key], wave-private

    const int t    = threadIdx.x;
    const int wave = t >> 6;        // 0..3
    const int lane = t & 63;
    const int quad = lane >> 4;
    const int l16  = lane & 15;
    // id = (31-qt)*32 + hb : big q-tiles dispatch first; id%8 == hb%8 (XCD)
    const int id  = blockIdx.x;
    const int qt  = 31 - (id >> 5);
    const int hb  = id & 31;
    const int h   = hb & 15;
    const int b   = hb >> 4;

    const int row0 = qt * 64 + wave * 16;  // this wave's first q row

    // staging decomposition: thread t -> rows (t>>3) and (t>>3)+32, 16B
    // col-block t&7; source col-block pre-swizzled so the linear LDS write
    // lands the swizzled layout: slot (r, cb) holds global block cb ^ (r&7).
    const int sr  = t >> 3;                  // 0..31
    const int scs = (t & 7) ^ (sr & 7);      // same for row sr+32

    const __hip_bfloat16* kbase = QK + (size_t)(b * SEQ_LEN) * LDQK + DM + h * HD;
    const __hip_bfloat16* vbase = Vtg + (size_t)((b * NH + h) * HD) * SEQ_LEN;

#define STAGE(BUF, KT)                                                          \
    {                                                                           \
        gload_lds16(kbase + (size_t)((KT) * 64 + sr) * LDQK + scs * 8,          \
                    (char*)&Ks[BUF][0] + t * 16);                               \
        gload_lds16(kbase + (size_t)((KT) * 64 + sr + 32) * LDQK + scs * 8,     \
                    (char*)&Ks[BUF][0] + (t + 256) * 16);                       \
        gload_lds16(vbase + (size_t)sr * SEQ_LEN + (KT) * 64 + scs * 8,         \
                    (char*)&Vs[BUF][0] + t * 16);                               \
        gload_lds16(vbase + (size_t)(sr + 32) * SEQ_LEN + (KT) * 64 + scs * 8,  \
                    (char*)&Vs[BUF][0] + (t + 256) * 16);                       \
    }

// swizzled 16B fragment read: row RR, col-block G (8 bf16 per block)
#define LDS_FRAG(BASE, RR, G)                                                   \
    (*(const bf16x8*)((const char*)(BASE) + (RR) * 128 + ((((G) ^ ((RR) & 7))) << 4)))

// one K-tile trip: S = QK^T, mask (diagonal tile only), p=exp(s), O += P V
#define TRIP(BUF, KT)                                                           \
    {                                                                           \
        bf16x8 kf[4][2];                                                        \
        _Pragma("unroll") for (int kb = 0; kb < 4; kb++) {                      \
            int rr = kb * 16 + l16;                                             \
            kf[kb][0] = LDS_FRAG(Ks[BUF], rr, quad);                            \
            kf[kb][1] = LDS_FRAG(Ks[BUF], rr, quad + 4);                        \
        }                                                                       \
        f32x4 s[4];                                                             \
        __builtin_amdgcn_s_setprio(1);                                          \
        _Pragma("unroll") for (int kb = 0; kb < 4; kb++) {                      \
            f32x4 z = {0.f, 0.f, 0.f, 0.f};                                     \
            z = __builtin_amdgcn_mfma_f32_16x16x32_bf16(qf0, kf[kb][0], z, 0, 0, 0); \
            z = __builtin_amdgcn_mfma_f32_16x16x32_bf16(qf1, kf[kb][1], z, 0, 0, 0); \
            s[kb] = z;                                                          \
        }                                                                       \
        __builtin_amdgcn_s_setprio(0);                                          \
        if ((KT) == qt) { /* causal mask on the diagonal tile */                \
            _Pragma("unroll") for (int kb = 0; kb < 4; kb++) {                  \
                int key = (KT) * 64 + kb * 16 + l16;                            \
                _Pragma("unroll") for (int r = 0; r < 4; r++) {                 \
                    int rowg = row0 + quad * 4 + r;                             \
                    if (key > rowg) s[kb][r] = -1e30f;                          \
                }                                                               \
            }                                                                   \
        }                                                                       \
        _Pragma("unroll") for (int r = 0; r < 4; r++) {                         \
            float p0 = __expf(s[0][r]);                                         \
            float p1 = __expf(s[1][r]);                                         \
            float p2 = __expf(s[2][r]);                                         \
            float p3 = __expf(s[3][r]);                                         \
            l_p[r] += (p0 + p1) + (p2 + p3);                                    \
            int prow = wave * 16 + quad * 4 + r;                                \
            Ps[prow][ 0 + l16] = f2b(p0);                                       \
            Ps[prow][16 + l16] = f2b(p1);                                       \
            Ps[prow][32 + l16] = f2b(p2);                                       \
            Ps[prow][48 + l16] = f2b(p3);                                       \
        }                                                                       \
        bf16x8 pf0 = *(const bf16x8*)&Ps[wave * 16 + l16][quad * 8];            \
        bf16x8 pf1 = *(const bf16x8*)&Ps[wave * 16 + l16][32 + quad * 8];       \
        __builtin_amdgcn_s_setprio(1);                                          \
        _Pragma("unroll") for (int db = 0; db < 4; db++) {                      \
            int rr = db * 16 + l16;                                             \
            bf16x8 vf0 = LDS_FRAG(Vs[BUF], rr, quad);                           \
            bf16x8 vf1 = LDS_FRAG(Vs[BUF], rr, quad + 4);                       \
            o[db] = __builtin_amdgcn_mfma_f32_16x16x32_bf16(pf0, vf0, o[db], 0, 0, 0); \
            o[db] = __builtin_amdgcn_mfma_f32_16x16x32_bf16(pf1, vf1, o[db], 0, 0, 0); \
        }                                                                       \
        __builtin_amdgcn_s_setprio(0);                                          \
    }

    bf16x8 qf0, qf1;
    {
        const __hip_bfloat16* qp =
            QK + (size_t)(b * SEQ_LEN + row0 + l16) * LDQK + h * HD + quad * 8;
        qf0 = *(const bf16x8*)qp;
        qf1 = *(const bf16x8*)(qp + 32);
    }
    f32x4 o[4];
    float l_p[4];
#pragma unroll
    for (int r = 0; r < 4; r++) { o[r] = (f32x4){0.f, 0.f, 0.f, 0.f}; l_p[r] = 0.f; }

    STAGE(0, 0);
    for (int kt = 0; kt <= qt; ++kt) {
        const int buf = kt & 1;
        __syncthreads();  // staging of buf drained; buf^1 free for reuse
        if (kt < qt) STAGE(buf ^ 1, kt + 1);  // async; hides under TRIP
        TRIP(buf, kt);
    }

    // ---- epilogue: reduce l across the 16-lane row group, normalize ----
#pragma unroll
    for (int r = 0; r < 4; r++) {
        float rs = l_p[r];
        rs += __shfl_xor(rs, 1);
        rs += __shfl_xor(rs, 2);
        rs += __shfl_xor(rs, 4);
        rs += __shfl_xor(rs, 8);
        float inv = 1.0f / rs;
        size_t ro = (size_t)(b * SEQ_LEN + row0 + quad * 4 + r) * DM + h * HD;
        O[ro +  0 + l16] = __float2bfloat16(o[0][r] * inv);
        O[ro + 16 + l16] = __float2bfloat16(o[1][r] * inv);
        O[ro + 32 + l16] = __float2bfloat16(o[2][r] * inv);
        O[ro + 48 + l16] = __float2bfloat16(o[3][r] * inv);
    }
#undef STAGE
#undef LDS_FRAG
#undef TRIP
}

// ---------------------------------------------------------------------------
// Workspace (40 MiB of 48):
//   [0,8)    xb [4096x1024] bf16, reused as Ab (attn output)
//   [8,14)   Wqkvb [3072x1024] bf16
//   [14,16)  Wob [1024x1024] bf16
//   [16,32)  QKb [4096x2048] bf16 (Q roped+scaled, K roped — fused in GEMM)
//   [32,40)  Vtg [2][16][64][2048] bf16
// ---------------------------------------------------------------------------
extern "C" void kernel_launch(void* const* d_in, const int* in_sizes, int n_in,
                              void* d_out, int out_size, void* d_ws, size_t ws_size,
                              hipStream_t stream) {
    const float* x  = (const float*)d_in[0];
    const float* Wq = (const float*)d_in[1];
    const float* Wk = (const float*)d_in[2];
    const float* Wv = (const float*)d_in[3];
    const float* Wo = (const float*)d_in[4];
    const int* pos = (const int*)d_in[6];
    float* out = (float*)d_out;

    char* w = (char*)d_ws;
    const size_t MiB = 1024 * 1024;
    __hip_bfloat16* xb    = (__hip_bfloat16*)(w + 0 * MiB);
    __hip_bfloat16* Ab    = (__hip_bfloat16*)(w + 0 * MiB);  // reuse after QKV gemm
    __hip_bfloat16* Wqkvb = (__hip_bfloat16*)(w + 8 * MiB);
    __hip_bfloat16* Wob   = (__hip_bfloat16*)(w + 14 * MiB);
    __hip_bfloat16* QKb   = (__hip_bfloat16*)(w + 16 * MiB);
    __hip_bfloat16* Vtg   = (__hip_bfloat16*)(w + 32 * MiB);

    cvt_all<<<8192, 256, 0, stream>>>(x, Wq, Wk, Wv, Wo, xb, Wqkvb, Wob);

    gemm128<__hip_bfloat16, true><<<dim3(NR / 128, NQKV / 128), 256, 0, stream>>>(
        xb, Wqkvb, QKb, DM, LDQK, Vtg, pos);

    attn_kernel<<<1024, 256, 0, stream>>>(QKb, Vtg, Ab);

    gemm128<float, false><<<dim3(NR / 128, DM / 128), 256, 0, stream>>>(
        Ab, Wob, out, DM, DM, nullptr, nullptr);
}